// Round 8
// baseline (720.526 us; speedup 1.0000x reference)
//
#include <hip/hip_runtime.h>

#define B_ 8
#define IMGSZ 224
#define PATCH 16
#define D_ 192
#define DEPTH_ 8
#define H_ 14
#define W_ 14
#define L_ 196
#define DIN 384
#define DSTATE 16
#define DCONV 4
#define DTR 12
#define NCLS_ 1000
#define EPS_ 1e-5f
#define ROWS_PER_DIR (B_*L_)      /* 1568 */
#define M_TOTAL (4*ROWS_PER_DIR)  /* 6272 */

typedef unsigned short ushort_t;
typedef unsigned int uint_t;
typedef __attribute__((ext_vector_type(8)))  short bf16x8;
typedef __attribute__((ext_vector_type(16))) float f32x16;

__device__ __forceinline__ ushort_t f2bf(float f) {
  uint_t u = __builtin_bit_cast(uint_t, f);
  u += 0x7fffu + ((u >> 16) & 1u);          // RNE
  return (ushort_t)(u >> 16);
}
__device__ __forceinline__ float bf2f(ushort_t s) {
  uint_t u = ((uint_t)s) << 16;
  return __builtin_bit_cast(float, u);
}

// ------------- one-shot f32->bf16 conversion of the 3 big weight arrays ---
__global__ __launch_bounds__(256) void k_cvt3(
    const float* __restrict__ s0, const float* __restrict__ s1,
    const float* __restrict__ s2, ushort_t* __restrict__ dst)
{
  int i = blockIdx.x*256 + threadIdx.x;         // float4 index
  if (i >= 1806336) return;
  const float* src;
  int off;
  if (i < 36864)        { src = s0; off = i; }
  else if (i < 1216512) { src = s1; off = i - 36864; }
  else                  { src = s2; off = i - 1216512; }
  float4 v = reinterpret_cast<const float4*>(src)[off];
  ushort4 o;
  o.x = f2bf(v.x); o.y = f2bf(v.y); o.z = f2bf(v.z); o.w = f2bf(v.w);
  reinterpret_cast<ushort4*>(dst)[i] = o;
}

// ---------------- x_proj_w [32][44][384] -> padded bf16 [32][64][384] -----
__global__ __launch_bounds__(256) void k_cvt_xw(const float* __restrict__ src,
                                                ushort_t* __restrict__ dst)
{
  int idx = blockIdx.x*256 + threadIdx.x;
  if (idx >= 32*64*384) return;
  int g = idx / (64*384);
  int r = (idx / 384) % 64;
  int k = idx % 384;
  float v = (r < 44) ? src[((size_t)g*44 + r)*384 + k] : 0.f;
  dst[idx] = f2bf(v);
}

// ---------------- im2col of 16x16 patches -> bf16 [1568][768] -------------
__global__ __launch_bounds__(256) void k_im2col(const float* __restrict__ x,
                                                ushort_t* __restrict__ Xp)
{
  int idx = blockIdx.x*256 + threadIdx.x;
  if (idx >= ROWS_PER_DIR*768) return;
  int row = idx / 768, k = idx - row*768;
  int b = row / L_, l = row - b*L_;
  int hh = l / W_, ww = l - hh*W_;
  int c = k >> 8, rem = k & 255, pi = rem >> 4, pj = rem & 15;
  float v = x[(((size_t)b*3 + c)*IMGSZ + hh*PATCH + pi)*IMGSZ + ww*PATCH + pj];
  Xp[idx] = f2bf(v);
}

// ------- MFMA bf16 GEMM, 32 rows x 64 cols per wave: C = X W^T ------------
// OBF=1: store bf16, else f32
template<int KT, int OBF>
__global__ __launch_bounds__(64) void k_gemm2(
    const ushort_t* __restrict__ X, const ushort_t* __restrict__ W,
    void* __restrict__ C, int N, int nb, int wstride, int rows_per_dir)
{
  int row0 = blockIdx.x*32, col0 = blockIdx.y*64;
  int dir = row0 / rows_per_dir;
  const ushort_t* Wp = W + (size_t)dir*wstride;
  int l = threadIdx.x;
  int r31 = l & 31, khalf = (l >> 5)*8;
  const ushort_t* aptr  = X  + (size_t)(row0 + r31)*KT + khalf;
  const ushort_t* b0ptr = Wp + (size_t)(col0 + r31)*KT + khalf;
  const ushort_t* b1ptr = b0ptr + (size_t)32*KT;
  f32x16 acc00 = {}, acc01 = {}, acc10 = {}, acc11 = {};
  #pragma unroll
  for (int k = 0; k < KT; k += 32) {
    bf16x8 a0 = *reinterpret_cast<const bf16x8*>(aptr + k);
    bf16x8 a1 = *reinterpret_cast<const bf16x8*>(aptr + k + 16);
    bf16x8 b00 = *reinterpret_cast<const bf16x8*>(b0ptr + k);
    bf16x8 b01 = *reinterpret_cast<const bf16x8*>(b0ptr + k + 16);
    bf16x8 b10 = *reinterpret_cast<const bf16x8*>(b1ptr + k);
    bf16x8 b11 = *reinterpret_cast<const bf16x8*>(b1ptr + k + 16);
    acc00 = __builtin_amdgcn_mfma_f32_32x32x16_bf16(a0, b00, acc00, 0, 0, 0);
    acc01 = __builtin_amdgcn_mfma_f32_32x32x16_bf16(a1, b01, acc01, 0, 0, 0);
    acc10 = __builtin_amdgcn_mfma_f32_32x32x16_bf16(a0, b10, acc10, 0, 0, 0);
    acc11 = __builtin_amdgcn_mfma_f32_32x32x16_bf16(a1, b11, acc11, 0, 0, 0);
  }
  int c0 = col0 + r31, c1 = col0 + 32 + r31;
  #pragma unroll
  for (int r = 0; r < 16; ++r) {
    int row = (r & 3) + 8*(r >> 2) + 4*(l >> 5);
    size_t base = (size_t)(row0 + row)*N;
    float v0 = acc00[r] + acc01[r];
    float v1 = acc10[r] + acc11[r];
    if (OBF) {
      ushort_t* crow = (ushort_t*)C + base;
      if (c0 < nb) crow[c0] = f2bf(v0);
      if (c1 < nb) crow[c1] = f2bf(v1);
    } else {
      float* crow = (float*)C + base;
      if (c0 < nb) crow[c0] = v0;
      if (c1 < nb) crow[c1] = v1;
    }
  }
}

// ------- patch LN + layer-0 LN + scatter residual/xln to 4 directions -----
__global__ __launch_bounds__(64) void k_peln(
    const float* __restrict__ Cp, const float* __restrict__ pb,
    const float* __restrict__ plw, const float* __restrict__ plb,
    const float* __restrict__ lnw, const float* __restrict__ lnb,
    float* __restrict__ residual, ushort_t* __restrict__ xln)
{
  int blk = blockIdx.x;            // b*L + l
  int b = blk / L_, l = blk - b*L_;
  int hh = l / W_, ww = l - hh*W_;
  int lane = threadIdx.x;
  float v[3]; float s = 0.f;
  #pragma unroll
  for (int i = 0; i < 3; ++i) {
    int d = lane + i*64;
    float t = Cp[(size_t)blk*D_ + d] + pb[d];
    v[i] = t; s += t;
  }
  #pragma unroll
  for (int off = 32; off; off >>= 1) s += __shfl_xor(s, off);
  float m = s*(1.f/D_); float q = 0.f;
  #pragma unroll
  for (int i = 0; i < 3; ++i) { float dd = v[i]-m; q += dd*dd; }
  #pragma unroll
  for (int off = 32; off; off >>= 1) q += __shfl_xor(q, off);
  float inv = rsqrtf(q*(1.f/D_)+EPS_);
  float nv[3]; s = 0.f;
  #pragma unroll
  for (int i = 0; i < 3; ++i) {
    int d = lane + i*64;
    nv[i] = (v[i]-m)*inv*plw[d] + plb[d];
    s += nv[i];
  }
  #pragma unroll
  for (int off = 32; off; off >>= 1) s += __shfl_xor(s, off);
  float m2 = s*(1.f/D_); q = 0.f;
  #pragma unroll
  for (int i = 0; i < 3; ++i) { float dd = nv[i]-m2; q += dd*dd; }
  #pragma unroll
  for (int off = 32; off; off >>= 1) q += __shfl_xor(q, off);
  float inv2 = rsqrtf(q*(1.f/D_)+EPS_);
  int l1 = ww*W_ + hh;
  size_t rr[4];
  rr[0] = ((size_t)(0*B_+b))*L_ + l;
  rr[1] = ((size_t)(1*B_+b))*L_ + l1;
  rr[2] = ((size_t)(2*B_+b))*L_ + (L_-1-l);
  rr[3] = ((size_t)(3*B_+b))*L_ + (L_-1-l1);
  #pragma unroll
  for (int i = 0; i < 3; ++i) {
    int d = lane + i*64;
    float nrm = (nv[i]-m2)*inv2;
    #pragma unroll
    for (int k = 0; k < 4; ++k) {
      residual[rr[k]*D_+d] = nv[i];
      xln[rr[k]*D_+d] = f2bf(nrm*lnw[(size_t)(k*DEPTH_)*D_+d] + lnb[(size_t)(k*DEPTH_)*D_+d]);
    }
  }
}

// ---- fused: causal conv(k=4)+SiLU (32 rows x 384 ch) -> u_bf, then -------
// ---- x_proj MFMA GEMM on the just-written rows (waves 0-1) -> xdbl -------
__global__ __launch_bounds__(256) void k_convxp(
    const ushort_t* __restrict__ xzb, const float* __restrict__ cw,
    const float* __restrict__ cb, const ushort_t* __restrict__ xw,
    ushort_t* __restrict__ ub, float* __restrict__ xdbl, int layer)
{
  int row0 = blockIdx.x*32;
  int dir = row0 / ROWS_PER_DIR;
  int tid = threadIdx.x;
  // ---- step 1: conv for 32 rows x 48 chan-groups (1536 items, 6 iters) ----
  #pragma unroll
  for (int it = 0; it < 6; ++it) {
    int wi = it*256 + tid;            // 0..1535
    int r = wi / 48, g = wi - r*48;
    int c8 = g*8;
    int row = row0 + r;
    int l = row % L_;
    size_t pbase = (size_t)(dir*DEPTH_+layer)*DIN + c8;
    float wv[32];
    #pragma unroll
    for (int i = 0; i < 8; ++i)
      ((float4*)wv)[i] = ((const float4*)(cw + pbase*DCONV))[i];
    float acc[8];
    #pragma unroll
    for (int i = 0; i < 2; ++i)
      ((float4*)acc)[i] = ((const float4*)(cb + pbase))[i];
    #pragma unroll
    for (int t = 0; t < DCONV; ++t) {
      int lt = l - 3 + t;
      if (lt >= 0) {
        bf16x8 xv = *reinterpret_cast<const bf16x8*>(xzb + (size_t)(row-3+t)*768 + c8);
        #pragma unroll
        for (int j = 0; j < 8; ++j)
          acc[j] += bf2f((ushort_t)xv[j]) * wv[j*4 + t];
      }
    }
    bf16x8 o;
    #pragma unroll
    for (int j = 0; j < 8; ++j) {
      float uv = acc[j] / (1.f + __expf(-acc[j]));
      o[j] = (short)f2bf(uv);
    }
    *reinterpret_cast<bf16x8*>(ub + (size_t)row*DIN + c8) = o;
  }
  __syncthreads();   // drains vmcnt; same-CU L1 -> writes visible to all waves
  // ---- step 2: x_proj GEMM (44 cols, padded to 64) on rows row0..row0+31 --
  int wv_ = tid >> 6;
  if (wv_ < 2) {
    int l = tid & 63;
    int r31 = l & 31, khalf = (l >> 5)*8;
    const ushort_t* aptr = ub + (size_t)(row0 + r31)*DIN + khalf;
    const ushort_t* bptr = xw + (size_t)(dir*DEPTH_+layer)*64*384
                              + (size_t)(wv_*32 + r31)*384 + khalf;
    f32x16 acc0 = {}, acc1 = {};
    #pragma unroll
    for (int k = 0; k < DIN; k += 32) {
      bf16x8 a0 = *reinterpret_cast<const bf16x8*>(aptr + k);
      bf16x8 b0 = *reinterpret_cast<const bf16x8*>(bptr + k);
      bf16x8 a1 = *reinterpret_cast<const bf16x8*>(aptr + k + 16);
      bf16x8 b1 = *reinterpret_cast<const bf16x8*>(bptr + k + 16);
      acc0 = __builtin_amdgcn_mfma_f32_32x32x16_bf16(a0, b0, acc0, 0, 0, 0);
      acc1 = __builtin_amdgcn_mfma_f32_32x32x16_bf16(a1, b1, acc1, 0, 0, 0);
    }
    int c = wv_*32 + r31;
    if (c < 44) {
      #pragma unroll
      for (int r = 0; r < 16; ++r) {
        int rr = (r & 3) + 8*(r >> 2) + 4*(l >> 5);
        xdbl[(size_t)(row0 + rr)*44 + c] = acc0[r] + acc1[r];
      }
    }
  }
}

// ------- selective scan with inline delta-proj + skip(D) + SiLU(z) gate ---
// block: 16 channels x 16 states; grid: 4*8*24; chunked, shuffle-free,
// double-buffered staging LDS (2 barriers per chunk).
#define SCHUNK 14
#define NCHUNK 14
__global__ __launch_bounds__(256, 3) void k_scan(
    const ushort_t* __restrict__ ub, const float* __restrict__ xdbl,
    const ushort_t* __restrict__ xzb,
    const float* __restrict__ Alog, const float* __restrict__ Dp,
    const float* __restrict__ dtw, const float* __restrict__ dtb,
    ushort_t* __restrict__ yg, int layer)
{
  int blk = blockIdx.x;
  int kdir = blk / (B_*24);
  int rem = blk % (B_*24);
  int b = rem / 24, dc = rem % 24;
  int tid = threadIdx.x;
  int st = tid & 15, ch = tid >> 4;           // compute mapping
  size_t pl = (size_t)(kdir*DEPTH_+layer)*DIN + dc*16 + ch;
  float a = -expf(Alog[pl*DSTATE + st]);
  size_t rowbase = ((size_t)kdir*B_ + b)*L_;

  int ll = tid >> 4, cc = tid & 15;           // loader/phase3 mapping
  bool ldr = tid < 224;
  size_t plc = (size_t)(kdir*DEPTH_+layer)*DIN + dc*16 + cc;
  float Dv3 = Dp[plc];
  float dwt[12]; float dbias = dtb[plc];
  #pragma unroll
  for (int i = 0; i < 3; ++i)
    ((float4*)dwt)[i] = ((const float4*)(dtw + plc*DTR))[i];

  __shared__ __align__(16) float sd[2][16][20], su[2][16][20], sB[2][16][20],
                                 sC[2][16][20], sz[2][16][20];
  __shared__ __align__(16) float sp[SCHUNK][16][20];

  float rd=0.f, ru=0.f, rB=0.f, rC=0.f, rz=0.f;
  if (ldr) {
    size_t r = rowbase + ll;
    float xv[12];
    #pragma unroll
    for (int i = 0; i < 3; ++i) ((float4*)xv)[i] = ((const float4*)(xdbl + r*44))[i];
    float acc = dbias;
    #pragma unroll
    for (int t = 0; t < DTR; ++t) acc += xv[t]*dwt[t];
    rd = (acc > 20.f) ? acc : log1pf(__expf(acc));
    ru = bf2f(ub[r*DIN + dc*16 + cc]);
    rB = xdbl[r*44 + DTR + cc];
    rC = xdbl[r*44 + DTR + DSTATE + cc];
    rz = bf2f(xzb[r*768 + DIN + dc*16 + cc]);
  }

  float h = 0.f;
  int cur = 0;
  for (int chk = 0; chk < NCHUNK; ++chk) {
    if (ldr) { sd[cur][cc][ll]=rd; su[cur][cc][ll]=ru; sB[cur][cc][ll]=rB;
               sC[cur][cc][ll]=rC; sz[cur][cc][ll]=rz; }
    __syncthreads();                           // (a) staging visible
    if (chk+1 < NCHUNK && ldr) {
      size_t r = rowbase + (chk+1)*SCHUNK + ll;
      float xv[12];
      #pragma unroll
      for (int i = 0; i < 3; ++i) ((float4*)xv)[i] = ((const float4*)(xdbl + r*44))[i];
      float acc = dbias;
      #pragma unroll
      for (int t = 0; t < DTR; ++t) acc += xv[t]*dwt[t];
      rd = (acc > 20.f) ? acc : log1pf(__expf(acc));
      ru = bf2f(ub[r*DIN + dc*16 + cc]);
      rB = xdbl[r*44 + DTR + cc];
      rC = xdbl[r*44 + DTR + DSTATE + cc];
      rz = bf2f(xzb[r*768 + DIN + dc*16 + cc]);
    }
    // phase 1: bulk-load coefficient rows, compute all E (parallel exps)
    float dlv[16], ulv[16], Bvv[16], Cvv[16];
    #pragma unroll
    for (int i = 0; i < 4; ++i) {
      ((float4*)dlv)[i] = ((const float4*)&sd[cur][ch][0])[i];
      ((float4*)ulv)[i] = ((const float4*)&su[cur][ch][0])[i];
      ((float4*)Bvv)[i] = ((const float4*)&sB[cur][st][0])[i];
      ((float4*)Cvv)[i] = ((const float4*)&sC[cur][st][0])[i];
    }
    float E[SCHUNK];
    #pragma unroll
    for (int l = 0; l < SCHUNK; ++l) E[l] = __expf(dlv[l]*a);
    // phase 2: 14-FMA recurrence chain, store h*C
    #pragma unroll
    for (int l = 0; l < SCHUNK; ++l) {
      h = h*E[l] + dlv[l]*ulv[l]*Bvv[l];
      sp[l][ch][st] = h*Cvv[l];
    }
    __syncthreads();                           // (b) sp visible
    // phase 3: reduce 16 states per (l, ch), gate, coalesced store
    if (ldr) {
      float pv[16];
      #pragma unroll
      for (int i = 0; i < 4; ++i)
        ((float4*)pv)[i] = ((const float4*)&sp[ll][cc][0])[i];
      float s = 0.f;
      #pragma unroll
      for (int i = 0; i < 16; ++i) s += pv[i];
      float ul = su[cur][cc][ll];
      float z  = sz[cur][cc][ll];
      float yv = (s + ul*Dv3) * (z / (1.f + __expf(-z)));
      yg[(rowbase + chk*SCHUNK + ll)*DIN + dc*16 + cc] = f2bf(yv);
    }
    cur ^= 1;   // next staging goes to the other buffer; no 3rd barrier
  }
}

// ------ fused out_proj GEMM + residual add + LN(layer+1) -> xln_bf --------
template<int LAST>
__global__ __launch_bounds__(384) void k_outln(
    const ushort_t* __restrict__ X, const ushort_t* __restrict__ W,
    float* __restrict__ residual,
    const float* __restrict__ lnw, const float* __restrict__ lnb,
    ushort_t* __restrict__ xln, int layer)
{
  int row0 = blockIdx.x*32;
  int dir = row0 / ROWS_PER_DIR;
  const ushort_t* Wp = W + (size_t)dir*(DEPTH_*D_*DIN);
  int tid = threadIdx.x;
  int wv = tid >> 6;           // 0..5 -> col tile
  int l  = tid & 63;
  int col0 = wv*32;
  int r31 = l & 31, khalf = (l >> 5)*8;
  const ushort_t* aptr = X  + (size_t)(row0 + r31)*DIN + khalf;
  const ushort_t* bptr = Wp + (size_t)(col0 + r31)*DIN + khalf;
  f32x16 acc0 = {}, acc1 = {};
  #pragma unroll
  for (int k = 0; k < DIN; k += 32) {
    bf16x8 a0 = *reinterpret_cast<const bf16x8*>(aptr + k);
    bf16x8 b0 = *reinterpret_cast<const bf16x8*>(bptr + k);
    bf16x8 a1 = *reinterpret_cast<const bf16x8*>(aptr + k + 16);
    bf16x8 b1 = *reinterpret_cast<const bf16x8*>(bptr + k + 16);
    acc0 = __builtin_amdgcn_mfma_f32_32x32x16_bf16(a0, b0, acc0, 0, 0, 0);
    acc1 = __builtin_amdgcn_mfma_f32_32x32x16_bf16(a1, b1, acc1, 0, 0, 0);
  }
  __shared__ __align__(16) float Cs[32][196];
  __shared__ float sred[32][12], qred[32][12], sm[32], si[32];
  #pragma unroll
  for (int r = 0; r < 16; ++r) {
    int row = (r & 3) + 8*(r >> 2) + 4*(l >> 5);
    Cs[row][col0 + r31] = acc0[r] + acc1[r];
  }
  __syncthreads();
  int rr = tid / 12, jj = tid - rr*12;
  int c0 = jj*16;
  float* resrow = residual + (size_t)(row0+rr)*D_ + c0;
  float v[16];
  float s = 0.f, q = 0.f;
  #pragma unroll
  for (int i = 0; i < 16; i += 4) {
    float4 rv = *reinterpret_cast<const float4*>(resrow + i);
    float4 cv = *reinterpret_cast<const float4*>(&Cs[rr][c0 + i]);
    v[i+0] = rv.x + cv.x; v[i+1] = rv.y + cv.y;
    v[i+2] = rv.z + cv.z; v[i+3] = rv.w + cv.w;
  }
  #pragma unroll
  for (int i = 0; i < 16; ++i) { s += v[i]; q += v[i]*v[i]; }
  #pragma unroll
  for (int i = 0; i < 16; i += 4) {
    float4 o = make_float4(v[i], v[i+1], v[i+2], v[i+3]);
    *reinterpret_cast<float4*>(resrow + i) = o;
  }
  if (!LAST) {
    sred[rr][jj] = s; qred[rr][jj] = q;
    __syncthreads();
    if (tid < 32) {
      float S = 0.f, Q = 0.f;
      #pragma unroll
      for (int j = 0; j < 12; ++j) { S += sred[tid][j]; Q += qred[tid][j]; }
      float m = S*(1.f/D_);
      float var = Q*(1.f/D_) - m*m;
      sm[tid] = m; si[tid] = rsqrtf(var + EPS_);
    }
    __syncthreads();
    float m = sm[rr], inv = si[rr];
    const float* w = lnw + (size_t)(dir*DEPTH_ + layer + 1)*D_ + c0;
    const float* bb = lnb + (size_t)(dir*DEPTH_ + layer + 1)*D_ + c0;
    ushort_t* xrow = xln + (size_t)(row0+rr)*D_ + c0;
    #pragma unroll
    for (int i = 0; i < 16; ++i)
      xrow[i] = f2bf((v[i]-m)*inv*w[i] + bb[i]);
  }
}

// ---------------- merge 4 directions + out_norm LN + head LN --------------
__global__ __launch_bounds__(64) void k_combine(
    const float* __restrict__ res,
    const float* __restrict__ onw, const float* __restrict__ onb,
    const float* __restrict__ hlw, const float* __restrict__ hlb,
    float* __restrict__ ynorm)
{
  int blk = blockIdx.x;
  int b = blk / L_, l = blk % L_;
  int hh = l / W_, ww = l % W_;
  int l1 = ww*W_ + hh;
  size_t r0 = ((size_t)(0*B_+b))*L_ + l;
  size_t r1 = ((size_t)(1*B_+b))*L_ + l1;
  size_t r2 = ((size_t)(2*B_+b))*L_ + (L_-1-l);
  size_t r3 = ((size_t)(3*B_+b))*L_ + (L_-1-l1);
  int lane = threadIdx.x;
  float v[3]; float s = 0.f;
  #pragma unroll
  for (int i=0;i<3;i++){
    int d = lane + i*64;
    float t = res[r0*D_+d] + res[r1*D_+d] + res[r2*D_+d] + res[r3*D_+d];
    v[i]=t; s+=t;
  }
  #pragma unroll
  for (int off=32;off;off>>=1) s += __shfl_xor(s,off);
  float m = s*(1.f/D_); float q=0.f;
  #pragma unroll
  for (int i=0;i<3;i++){ float dd=v[i]-m; q+=dd*dd; }
  #pragma unroll
  for (int off=32;off;off>>=1) q += __shfl_xor(q,off);
  float inv = rsqrtf(q*(1.f/D_)+EPS_);
  float v2[3]; s = 0.f;
  #pragma unroll
  for (int i=0;i<3;i++){ int d=lane+i*64; float t=(v[i]-m)*inv*onw[d]+onb[d]; v2[i]=t; s+=t; }
  #pragma unroll
  for (int off=32;off;off>>=1) s += __shfl_xor(s,off);
  float m2 = s*(1.f/D_); q=0.f;
  #pragma unroll
  for (int i=0;i<3;i++){ float dd=v2[i]-m2; q+=dd*dd; }
  #pragma unroll
  for (int off=32;off;off>>=1) q += __shfl_xor(q,off);
  float inv2 = rsqrtf(q*(1.f/D_)+EPS_);
  #pragma unroll
  for (int i=0;i<3;i++){ int d=lane+i*64; ynorm[((size_t)b*L_+l)*D_+d] = (v2[i]-m2)*inv2*hlw[d]+hlb[d]; }
}

// ---------------- mean over L ---------------------------------------------
__global__ __launch_bounds__(192) void k_mean(const float* __restrict__ ynorm, float* __restrict__ ybar)
{
  int b = blockIdx.x, d = threadIdx.x;
  float s = 0.f;
  for (int l = 0; l < L_; ++l) s += ynorm[((size_t)b*L_+l)*D_ + d];
  ybar[b*D_+d] = s * (1.f/L_);
}

// ---------------- classifier head -----------------------------------------
__global__ __launch_bounds__(256) void k_head(
    const float* __restrict__ ybar, const float* __restrict__ hw, const float* __restrict__ hb,
    float* __restrict__ out)
{
  __shared__ float ys[D_];
  int b = blockIdx.x >> 2;
  int c = (blockIdx.x & 3)*256 + threadIdx.x;
  for (int i = threadIdx.x; i < D_; i += 256) ys[i] = ybar[b*D_+i];
  __syncthreads();
  if (c < NCLS_) {
    float acc = hb[c];
    const float* wr = hw + (size_t)c*D_;
    for (int dd = 0; dd < D_; dd += 4) {
      float4 a4 = *reinterpret_cast<const float4*>(&ys[dd]);
      float4 b4 = *reinterpret_cast<const float4*>(&wr[dd]);
      acc += a4.x*b4.x + a4.y*b4.y + a4.z*b4.z + a4.w*b4.w;
    }
    out[(size_t)b*NCLS_ + c] = acc;
  }
}

extern "C" void kernel_launch(void* const* d_in, const int* in_sizes, int n_in,
                              void* d_out, int out_size, void* d_ws, size_t ws_size,
                              hipStream_t stream)
{
  const float* x          = (const float*)d_in[0];
  const float* patch_w    = (const float*)d_in[1];
  const float* patch_b    = (const float*)d_in[2];
  const float* pe_ln_w    = (const float*)d_in[3];
  const float* pe_ln_b    = (const float*)d_in[4];
  const float* ln_w       = (const float*)d_in[5];
  const float* ln_b       = (const float*)d_in[6];
  const float* in_proj_w  = (const float*)d_in[7];
  const float* conv_w     = (const float*)d_in[8];
  const float* conv_b     = (const float*)d_in[9];
  const float* x_proj_w   = (const float*)d_in[10];
  const float* dt_w       = (const float*)d_in[11];
  const float* dt_b       = (const float*)d_in[12];
  const float* A_log      = (const float*)d_in[13];
  const float* Dp         = (const float*)d_in[14];
  const float* out_proj_w = (const float*)d_in[15];
  const float* out_norm_w = (const float*)d_in[16];
  const float* out_norm_b = (const float*)d_in[17];
  const float* head_ln_w  = (const float*)d_in[18];
  const float* head_ln_b  = (const float*)d_in[19];
  const float* head_w     = (const float*)d_in[20];
  const float* head_b     = (const float*)d_in[21];
  float* out = (float*)d_out;

  float* ws = (float*)d_ws;
  float*    residual = ws;                          // 1,204,224 f32
  ushort_t* xz_bf    = (ushort_t*)(residual + 1204224); // 4,816,896 ush
  ushort_t* u_bf     = xz_bf + 4816896;             // 2,408,448 ush
  float*    xdbl     = (float*)(u_bf + 2408448);    //   275,968 f32
  ushort_t* yg_bf    = (ushort_t*)(xdbl + 275968);  // 2,408,448 ush
  ushort_t* xln_bf   = yg_bf + 2408448;             // 1,204,224 ush
  ushort_t* wbf      = xln_bf + 1204224;
  ushort_t* pw_bf    = wbf;                         //   147,456 ush
  ushort_t* inw_bf   = wbf + 147456;                // 4,718,592 ush
  ushort_t* outw_bf  = inw_bf + 4718592;            // 2,359,296 ush
  ushort_t* xw_bf    = outw_bf + 2359296;           //   786,432 ush
  // patch-phase aliases inside xz region (not yet written):
  ushort_t* Xp       = xz_bf;                       // 1,204,224 ush
  float*    C_patch  = (float*)(xz_bf + 1204224);   //   301,056 f32
  // tail aliases inside yg region (dead after last outln):
  float*    ynorm    = (float*)yg_bf;               //   301,056 f32
  float*    ybar     = ynorm + 301056;              //     1,536 f32

  // weight conversions
  k_cvt3<<<(1806336+255)/256, 256, 0, stream>>>(patch_w, in_proj_w, out_proj_w, wbf);
  k_cvt_xw<<<(32*64*384+255)/256, 256, 0, stream>>>(x_proj_w, xw_bf);

  // patch embed: im2col -> mfma gemm -> double LN + scatter
  k_im2col<<<(ROWS_PER_DIR*768+255)/256, 256, 0, stream>>>(x, Xp);
  k_gemm2<768,0><<<dim3(ROWS_PER_DIR/32, 3), 64, 0, stream>>>(
      Xp, pw_bf, C_patch, D_, D_, 0, ROWS_PER_DIR);
  k_peln<<<ROWS_PER_DIR, 64, 0, stream>>>(C_patch, patch_b, pe_ln_w, pe_ln_b,
                                          ln_w, ln_b, residual, xln_bf);

  for (int layer = 0; layer < DEPTH_; ++layer) {
    k_gemm2<192,1><<<dim3(M_TOTAL/32, 12), 64, 0, stream>>>(
        xln_bf, inw_bf + (size_t)layer*768*D_, xz_bf, 768, 768, DEPTH_*768*D_, ROWS_PER_DIR);
    k_convxp<<<M_TOTAL/32, 256, 0, stream>>>(
        xz_bf, conv_w, conv_b, xw_bf, u_bf, xdbl, layer);
    k_scan<<<4*B_*24, 256, 0, stream>>>(
        u_bf, xdbl, xz_bf, A_log, Dp, dt_w, dt_b, yg_bf, layer);
    if (layer < DEPTH_-1)
      k_outln<0><<<M_TOTAL/32, 384, 0, stream>>>(
          yg_bf, outw_bf, residual, ln_w, ln_b, xln_bf, layer);
    else
      k_outln<1><<<M_TOTAL/32, 384, 0, stream>>>(
          yg_bf, outw_bf, residual, ln_w, ln_b, xln_bf, layer);
  }

  k_combine<<<B_*L_, 64, 0, stream>>>(residual, out_norm_w, out_norm_b,
                                      head_ln_w, head_ln_b, ynorm);
  k_mean<<<B_, 192, 0, stream>>>(ynorm, ybar);
  k_head<<<B_*4, 256, 0, stream>>>(ybar, head_w, head_b, out);
}

// Round 9
// 674.897 us; speedup vs baseline: 1.0676x; 1.0676x over previous
//
#include <hip/hip_runtime.h>

#define B_ 8
#define IMGSZ 224
#define PATCH 16
#define D_ 192
#define DEPTH_ 8
#define H_ 14
#define W_ 14
#define L_ 196
#define DIN 384
#define DSTATE 16
#define DCONV 4
#define DTR 12
#define NCLS_ 1000
#define EPS_ 1e-5f
#define ROWS_PER_DIR (B_*L_)      /* 1568 */
#define M_TOTAL (4*ROWS_PER_DIR)  /* 6272 */

typedef unsigned short ushort_t;
typedef unsigned int uint_t;
typedef __attribute__((ext_vector_type(8)))  short bf16x8;
typedef __attribute__((ext_vector_type(16))) float f32x16;

__device__ __forceinline__ ushort_t f2bf(float f) {
  uint_t u = __builtin_bit_cast(uint_t, f);
  u += 0x7fffu + ((u >> 16) & 1u);          // RNE
  return (ushort_t)(u >> 16);
}

// ------------- one-shot f32->bf16 conversion of the 3 big weight arrays ---
// dst regions are contiguous: [patch 147456][in_proj 4718592][out_proj 2359296]
__global__ __launch_bounds__(256) void k_cvt3(
    const float* __restrict__ s0, const float* __restrict__ s1,
    const float* __restrict__ s2, ushort_t* __restrict__ dst)
{
  int i = blockIdx.x*256 + threadIdx.x;         // float4 index
  if (i >= 1806336) return;
  const float* src;
  int off;
  if (i < 36864)        { src = s0; off = i; }
  else if (i < 1216512) { src = s1; off = i - 36864; }
  else                  { src = s2; off = i - 1216512; }
  float4 v = reinterpret_cast<const float4*>(src)[off];
  ushort4 o;
  o.x = f2bf(v.x); o.y = f2bf(v.y); o.z = f2bf(v.z); o.w = f2bf(v.w);
  reinterpret_cast<ushort4*>(dst)[i] = o;
}

// ---------------- x_proj_w [32][44][384] -> padded bf16 [32][64][384] -----
__global__ __launch_bounds__(256) void k_cvt_xw(const float* __restrict__ src,
                                                ushort_t* __restrict__ dst)
{
  int idx = blockIdx.x*256 + threadIdx.x;
  if (idx >= 32*64*384) return;
  int g = idx / (64*384);
  int r = (idx / 384) % 64;
  int k = idx % 384;
  float v = (r < 44) ? src[((size_t)g*44 + r)*384 + k] : 0.f;
  dst[idx] = f2bf(v);
}

// ---------------- im2col of 16x16 patches -> bf16 [1568][768] -------------
__global__ __launch_bounds__(256) void k_im2col(const float* __restrict__ x,
                                                ushort_t* __restrict__ Xp)
{
  int idx = blockIdx.x*256 + threadIdx.x;
  if (idx >= ROWS_PER_DIR*768) return;
  int row = idx / 768, k = idx - row*768;
  int b = row / L_, l = row - b*L_;
  int hh = l / W_, ww = l - hh*W_;
  int c = k >> 8, rem = k & 255, pi = rem >> 4, pj = rem & 15;
  float v = x[(((size_t)b*3 + c)*IMGSZ + hh*PATCH + pi)*IMGSZ + ww*PATCH + pj];
  Xp[idx] = f2bf(v);
}

// ------- MFMA bf16 GEMM, 32 rows x 64 cols per wave: C = X W^T (f32) ------
template<int KT>
__global__ __launch_bounds__(64) void k_gemm2(
    const ushort_t* __restrict__ X, const ushort_t* __restrict__ W,
    float* __restrict__ C, int N, int nb, int wstride, int rows_per_dir)
{
  int row0 = blockIdx.x*32, col0 = blockIdx.y*64;
  int dir = row0 / rows_per_dir;
  const ushort_t* Wp = W + (size_t)dir*wstride;
  int l = threadIdx.x;
  int r31 = l & 31, khalf = (l >> 5)*8;
  const ushort_t* aptr  = X  + (size_t)(row0 + r31)*KT + khalf;
  const ushort_t* b0ptr = Wp + (size_t)(col0 + r31)*KT + khalf;
  const ushort_t* b1ptr = b0ptr + (size_t)32*KT;
  f32x16 acc00 = {}, acc01 = {}, acc10 = {}, acc11 = {};
  #pragma unroll
  for (int k = 0; k < KT; k += 32) {
    bf16x8 a0 = *reinterpret_cast<const bf16x8*>(aptr + k);
    bf16x8 a1 = *reinterpret_cast<const bf16x8*>(aptr + k + 16);
    bf16x8 b00 = *reinterpret_cast<const bf16x8*>(b0ptr + k);
    bf16x8 b01 = *reinterpret_cast<const bf16x8*>(b0ptr + k + 16);
    bf16x8 b10 = *reinterpret_cast<const bf16x8*>(b1ptr + k);
    bf16x8 b11 = *reinterpret_cast<const bf16x8*>(b1ptr + k + 16);
    acc00 = __builtin_amdgcn_mfma_f32_32x32x16_bf16(a0, b00, acc00, 0, 0, 0);
    acc01 = __builtin_amdgcn_mfma_f32_32x32x16_bf16(a1, b01, acc01, 0, 0, 0);
    acc10 = __builtin_amdgcn_mfma_f32_32x32x16_bf16(a0, b10, acc10, 0, 0, 0);
    acc11 = __builtin_amdgcn_mfma_f32_32x32x16_bf16(a1, b11, acc11, 0, 0, 0);
  }
  int c0 = col0 + r31, c1 = col0 + 32 + r31;
  #pragma unroll
  for (int r = 0; r < 16; ++r) {
    int row = (r & 3) + 8*(r >> 2) + 4*(l >> 5);
    float* crow = C + (size_t)(row0 + row)*N;
    if (c0 < nb) crow[c0] = acc00[r] + acc01[r];
    if (c1 < nb) crow[c1] = acc10[r] + acc11[r];
  }
}

// ------- patch LN + layer-0 LN + scatter residual/xln to 4 directions -----
__global__ __launch_bounds__(64) void k_peln(
    const float* __restrict__ Cp, const float* __restrict__ pb,
    const float* __restrict__ plw, const float* __restrict__ plb,
    const float* __restrict__ lnw, const float* __restrict__ lnb,
    float* __restrict__ residual, ushort_t* __restrict__ xln)
{
  int blk = blockIdx.x;            // b*L + l
  int b = blk / L_, l = blk - b*L_;
  int hh = l / W_, ww = l - hh*W_;
  int lane = threadIdx.x;
  float v[3]; float s = 0.f;
  #pragma unroll
  for (int i = 0; i < 3; ++i) {
    int d = lane + i*64;
    float t = Cp[(size_t)blk*D_ + d] + pb[d];
    v[i] = t; s += t;
  }
  #pragma unroll
  for (int off = 32; off; off >>= 1) s += __shfl_xor(s, off);
  float m = s*(1.f/D_); float q = 0.f;
  #pragma unroll
  for (int i = 0; i < 3; ++i) { float dd = v[i]-m; q += dd*dd; }
  #pragma unroll
  for (int off = 32; off; off >>= 1) q += __shfl_xor(q, off);
  float inv = rsqrtf(q*(1.f/D_)+EPS_);
  // token embedding nv
  float nv[3]; s = 0.f;
  #pragma unroll
  for (int i = 0; i < 3; ++i) {
    int d = lane + i*64;
    nv[i] = (v[i]-m)*inv*plw[d] + plb[d];
    s += nv[i];
  }
  // layer-0 LN stats over nv
  #pragma unroll
  for (int off = 32; off; off >>= 1) s += __shfl_xor(s, off);
  float m2 = s*(1.f/D_); q = 0.f;
  #pragma unroll
  for (int i = 0; i < 3; ++i) { float dd = nv[i]-m2; q += dd*dd; }
  #pragma unroll
  for (int off = 32; off; off >>= 1) q += __shfl_xor(q, off);
  float inv2 = rsqrtf(q*(1.f/D_)+EPS_);
  int l1 = ww*W_ + hh;
  size_t rr[4];
  rr[0] = ((size_t)(0*B_+b))*L_ + l;
  rr[1] = ((size_t)(1*B_+b))*L_ + l1;
  rr[2] = ((size_t)(2*B_+b))*L_ + (L_-1-l);
  rr[3] = ((size_t)(3*B_+b))*L_ + (L_-1-l1);
  #pragma unroll
  for (int i = 0; i < 3; ++i) {
    int d = lane + i*64;
    float nrm = (nv[i]-m2)*inv2;
    #pragma unroll
    for (int k = 0; k < 4; ++k) {
      residual[rr[k]*D_+d] = nv[i];
      xln[rr[k]*D_+d] = f2bf(nrm*lnw[(size_t)(k*DEPTH_)*D_+d] + lnb[(size_t)(k*DEPTH_)*D_+d]);
    }
  }
}

// ---------------- causal depthwise conv (k=4) + bias + SiLU, float4 -------
// writes f32 u (for scan) and bf16 u (for x_proj MFMA GEMM)
__global__ __launch_bounds__(256) void k_conv(
    const float* __restrict__ xz, const float* __restrict__ cw, const float* __restrict__ cb,
    float* __restrict__ u, ushort_t* __restrict__ ub, int layer)
{
  int idx = blockIdx.x*256 + threadIdx.x;
  if (idx >= M_TOTAL*96) return;
  int row = idx / 96, d4 = (idx - row*96)*4;
  int kdir = row / ROWS_PER_DIR;
  int l = row % L_;
  size_t pbase = (size_t)(kdir*DEPTH_+layer)*DIN + d4;
  const float* cwp = cw + pbase*DCONV;
  float wv[16];
  #pragma unroll
  for (int i = 0; i < 4; ++i)
    ((float4*)wv)[i] = ((const float4*)cwp)[i];
  float4 bias = *reinterpret_cast<const float4*>(&cb[pbase]);
  float acc[4] = {bias.x, bias.y, bias.z, bias.w};
  #pragma unroll
  for (int t = 0; t < DCONV; ++t) {
    int ll = l - 3 + t;
    if (ll >= 0) {
      float4 xv = *reinterpret_cast<const float4*>(&xz[((size_t)row + (ll - l))*768 + d4]);
      acc[0] += xv.x * wv[0*4 + t];
      acc[1] += xv.y * wv[1*4 + t];
      acc[2] += xv.z * wv[2*4 + t];
      acc[3] += xv.w * wv[3*4 + t];
    }
  }
  float4 o; ushort4 ob;
  o.x = acc[0] / (1.f + __expf(-acc[0]));
  o.y = acc[1] / (1.f + __expf(-acc[1]));
  o.z = acc[2] / (1.f + __expf(-acc[2]));
  o.w = acc[3] / (1.f + __expf(-acc[3]));
  ob.x = f2bf(o.x); ob.y = f2bf(o.y); ob.z = f2bf(o.z); ob.w = f2bf(o.w);
  *reinterpret_cast<float4*>(&u[(size_t)row*DIN + d4]) = o;
  *reinterpret_cast<ushort4*>(&ub[(size_t)row*DIN + d4]) = ob;
}

// ------- selective scan with inline delta-proj + skip(D) + SiLU(z) gate ---
// block: 16 channels x 16 states; grid: 4*8*24; chunked, shuffle-free.
#define SCHUNK 14
#define NCHUNK 14
__global__ __launch_bounds__(256, 3) void k_scan(
    const float* __restrict__ u, const float* __restrict__ xdbl,
    const float* __restrict__ xz,
    const float* __restrict__ Alog, const float* __restrict__ Dp,
    const float* __restrict__ dtw, const float* __restrict__ dtb,
    ushort_t* __restrict__ yg, int layer)
{
  int blk = blockIdx.x;
  int kdir = blk / (B_*24);
  int rem = blk % (B_*24);
  int b = rem / 24, dc = rem % 24;
  int tid = threadIdx.x;
  int st = tid & 15, ch = tid >> 4;           // compute mapping
  size_t pl = (size_t)(kdir*DEPTH_+layer)*DIN + dc*16 + ch;
  float a = -expf(Alog[pl*DSTATE + st]);
  size_t rowbase = ((size_t)kdir*B_ + b)*L_;

  int ll = tid >> 4, cc = tid & 15;           // loader/phase3 mapping
  bool ldr = tid < 224;
  size_t plc = (size_t)(kdir*DEPTH_+layer)*DIN + dc*16 + cc;
  float Dv3 = Dp[plc];
  // per-thread dt weights (channel cc) for inline delta
  float dwt[12]; float dbias = dtb[plc];
  #pragma unroll
  for (int i = 0; i < 3; ++i)
    ((float4*)dwt)[i] = ((const float4*)(dtw + plc*DTR))[i];

  __shared__ __align__(16) float sd[16][20], su[16][20], sB[16][20],
                                 sC[16][20], sz[16][20];
  __shared__ __align__(16) float sp[SCHUNK][16][20];

  float rd=0.f, ru=0.f, rB=0.f, rC=0.f, rz=0.f;
  if (ldr) {
    size_t r = rowbase + ll;
    float xv[12];
    #pragma unroll
    for (int i = 0; i < 3; ++i) ((float4*)xv)[i] = ((const float4*)(xdbl + r*44))[i];
    float acc = dbias;
    #pragma unroll
    for (int t = 0; t < DTR; ++t) acc += xv[t]*dwt[t];
    rd = (acc > 20.f) ? acc : log1pf(__expf(acc));
    ru = u[r*DIN + dc*16 + cc];
    rB = xdbl[r*44 + DTR + cc];
    rC = xdbl[r*44 + DTR + DSTATE + cc];
    rz = xz[r*768 + DIN + dc*16 + cc];
  }

  float h = 0.f;
  for (int chk = 0; chk < NCHUNK; ++chk) {
    if (ldr) { sd[cc][ll]=rd; su[cc][ll]=ru; sB[cc][ll]=rB; sC[cc][ll]=rC; sz[cc][ll]=rz; }
    __syncthreads();
    if (chk+1 < NCHUNK && ldr) {
      size_t r = rowbase + (chk+1)*SCHUNK + ll;
      float xv[12];
      #pragma unroll
      for (int i = 0; i < 3; ++i) ((float4*)xv)[i] = ((const float4*)(xdbl + r*44))[i];
      float acc = dbias;
      #pragma unroll
      for (int t = 0; t < DTR; ++t) acc += xv[t]*dwt[t];
      rd = (acc > 20.f) ? acc : log1pf(__expf(acc));
      ru = u[r*DIN + dc*16 + cc];
      rB = xdbl[r*44 + DTR + cc];
      rC = xdbl[r*44 + DTR + DSTATE + cc];
      rz = xz[r*768 + DIN + dc*16 + cc];
    }
    // phase 1: bulk-load coefficient rows, compute all E (parallel exps)
    float dlv[16], ulv[16], Bvv[16], Cvv[16];
    #pragma unroll
    for (int i = 0; i < 4; ++i) {
      ((float4*)dlv)[i] = ((const float4*)&sd[ch][0])[i];
      ((float4*)ulv)[i] = ((const float4*)&su[ch][0])[i];
      ((float4*)Bvv)[i] = ((const float4*)&sB[st][0])[i];
      ((float4*)Cvv)[i] = ((const float4*)&sC[st][0])[i];
    }
    float E[SCHUNK];
    #pragma unroll
    for (int l = 0; l < SCHUNK; ++l) E[l] = __expf(dlv[l]*a);
    // phase 2: 14-FMA recurrence chain, store h*C
    #pragma unroll
    for (int l = 0; l < SCHUNK; ++l) {
      h = h*E[l] + dlv[l]*ulv[l]*Bvv[l];
      sp[l][ch][st] = h*Cvv[l];
    }
    __syncthreads();
    // phase 3: reduce 16 states per (l, ch), gate, coalesced store
    if (ldr) {
      float pv[16];
      #pragma unroll
      for (int i = 0; i < 4; ++i)
        ((float4*)pv)[i] = ((const float4*)&sp[ll][cc][0])[i];
      float s = 0.f;
      #pragma unroll
      for (int i = 0; i < 16; ++i) s += pv[i];
      float ul = su[cc][ll];
      float z  = sz[cc][ll];
      float yv = (s + ul*Dv3) * (z / (1.f + __expf(-z)));
      yg[(rowbase + chk*SCHUNK + ll)*DIN + dc*16 + cc] = f2bf(yv);
    }
    __syncthreads();
  }
}

// ------ fused out_proj GEMM + residual add + LN(layer+1) -> xln_bf --------
// grid 196 blocks x 384 threads (6 waves, one 32x32 col tile each)
template<int LAST>
__global__ __launch_bounds__(384) void k_outln(
    const ushort_t* __restrict__ X, const ushort_t* __restrict__ W,
    float* __restrict__ residual,
    const float* __restrict__ lnw, const float* __restrict__ lnb,
    ushort_t* __restrict__ xln, int layer)
{
  int row0 = blockIdx.x*32;
  int dir = row0 / ROWS_PER_DIR;
  const ushort_t* Wp = W + (size_t)dir*(DEPTH_*D_*DIN);
  int tid = threadIdx.x;
  int wv = tid >> 6;           // 0..5 -> col tile
  int l  = tid & 63;
  int col0 = wv*32;
  int r31 = l & 31, khalf = (l >> 5)*8;
  const ushort_t* aptr = X  + (size_t)(row0 + r31)*DIN + khalf;
  const ushort_t* bptr = Wp + (size_t)(col0 + r31)*DIN + khalf;
  f32x16 acc0 = {}, acc1 = {};
  #pragma unroll
  for (int k = 0; k < DIN; k += 32) {
    bf16x8 a0 = *reinterpret_cast<const bf16x8*>(aptr + k);
    bf16x8 b0 = *reinterpret_cast<const bf16x8*>(bptr + k);
    bf16x8 a1 = *reinterpret_cast<const bf16x8*>(aptr + k + 16);
    bf16x8 b1 = *reinterpret_cast<const bf16x8*>(bptr + k + 16);
    acc0 = __builtin_amdgcn_mfma_f32_32x32x16_bf16(a0, b0, acc0, 0, 0, 0);
    acc1 = __builtin_amdgcn_mfma_f32_32x32x16_bf16(a1, b1, acc1, 0, 0, 0);
  }
  __shared__ __align__(16) float Cs[32][196];
  __shared__ float sred[32][12], qred[32][12], sm[32], si[32];
  #pragma unroll
  for (int r = 0; r < 16; ++r) {
    int row = (r & 3) + 8*(r >> 2) + 4*(l >> 5);
    Cs[row][col0 + r31] = acc0[r] + acc1[r];
  }
  __syncthreads();
  // epilogue: 32 rows x 12 threads x 16 cols
  int rr = tid / 12, jj = tid - rr*12;
  int c0 = jj*16;
  float* resrow = residual + (size_t)(row0+rr)*D_ + c0;
  float v[16];
  float s = 0.f, q = 0.f;
  #pragma unroll
  for (int i = 0; i < 16; i += 4) {
    float4 rv = *reinterpret_cast<const float4*>(resrow + i);
    float4 cv = *reinterpret_cast<const float4*>(&Cs[rr][c0 + i]);
    v[i+0] = rv.x + cv.x; v[i+1] = rv.y + cv.y;
    v[i+2] = rv.z + cv.z; v[i+3] = rv.w + cv.w;
  }
  #pragma unroll
  for (int i = 0; i < 16; ++i) { s += v[i]; q += v[i]*v[i]; }
  // store residual_new
  #pragma unroll
  for (int i = 0; i < 16; i += 4) {
    float4 o = make_float4(v[i], v[i+1], v[i+2], v[i+3]);
    *reinterpret_cast<float4*>(resrow + i) = o;
  }
  if (!LAST) {
    sred[rr][jj] = s; qred[rr][jj] = q;
    __syncthreads();
    if (tid < 32) {
      float S = 0.f, Q = 0.f;
      #pragma unroll
      for (int j = 0; j < 12; ++j) { S += sred[tid][j]; Q += qred[tid][j]; }
      float m = S*(1.f/D_);
      float var = Q*(1.f/D_) - m*m;
      sm[tid] = m; si[tid] = rsqrtf(var + EPS_);
    }
    __syncthreads();
    float m = sm[rr], inv = si[rr];
    const float* w = lnw + (size_t)(dir*DEPTH_ + layer + 1)*D_ + c0;
    const float* bb = lnb + (size_t)(dir*DEPTH_ + layer + 1)*D_ + c0;
    ushort_t* xrow = xln + (size_t)(row0+rr)*D_ + c0;
    #pragma unroll
    for (int i = 0; i < 16; ++i)
      xrow[i] = f2bf((v[i]-m)*inv*w[i] + bb[i]);
  }
}

// ---------------- merge 4 directions + out_norm LN + head LN --------------
__global__ __launch_bounds__(64) void k_combine(
    const float* __restrict__ res,
    const float* __restrict__ onw, const float* __restrict__ onb,
    const float* __restrict__ hlw, const float* __restrict__ hlb,
    float* __restrict__ ynorm)
{
  int blk = blockIdx.x;
  int b = blk / L_, l = blk % L_;
  int hh = l / W_, ww = l % W_;
  int l1 = ww*W_ + hh;
  size_t r0 = ((size_t)(0*B_+b))*L_ + l;
  size_t r1 = ((size_t)(1*B_+b))*L_ + l1;
  size_t r2 = ((size_t)(2*B_+b))*L_ + (L_-1-l);
  size_t r3 = ((size_t)(3*B_+b))*L_ + (L_-1-l1);
  int lane = threadIdx.x;
  float v[3]; float s = 0.f;
  #pragma unroll
  for (int i=0;i<3;i++){
    int d = lane + i*64;
    float t = res[r0*D_+d] + res[r1*D_+d] + res[r2*D_+d] + res[r3*D_+d];
    v[i]=t; s+=t;
  }
  #pragma unroll
  for (int off=32;off;off>>=1) s += __shfl_xor(s,off);
  float m = s*(1.f/D_); float q=0.f;
  #pragma unroll
  for (int i=0;i<3;i++){ float dd=v[i]-m; q+=dd*dd; }
  #pragma unroll
  for (int off=32;off;off>>=1) q += __shfl_xor(q,off);
  float inv = rsqrtf(q*(1.f/D_)+EPS_);
  float v2[3]; s = 0.f;
  #pragma unroll
  for (int i=0;i<3;i++){ int d=lane+i*64; float t=(v[i]-m)*inv*onw[d]+onb[d]; v2[i]=t; s+=t; }
  #pragma unroll
  for (int off=32;off;off>>=1) s += __shfl_xor(s,off);
  float m2 = s*(1.f/D_); q=0.f;
  #pragma unroll
  for (int i=0;i<3;i++){ float dd=v2[i]-m2; q+=dd*dd; }
  #pragma unroll
  for (int off=32;off;off>>=1) q += __shfl_xor(q,off);
  float inv2 = rsqrtf(q*(1.f/D_)+EPS_);
  #pragma unroll
  for (int i=0;i<3;i++){ int d=lane+i*64; ynorm[((size_t)b*L_+l)*D_+d] = (v2[i]-m2)*inv2*hlw[d]+hlb[d]; }
}

// ---------------- mean over L ---------------------------------------------
__global__ __launch_bounds__(192) void k_mean(const float* __restrict__ ynorm, float* __restrict__ ybar)
{
  int b = blockIdx.x, d = threadIdx.x;
  float s = 0.f;
  for (int l = 0; l < L_; ++l) s += ynorm[((size_t)b*L_+l)*D_ + d];
  ybar[b*D_+d] = s * (1.f/L_);
}

// ---------------- classifier head -----------------------------------------
__global__ __launch_bounds__(256) void k_head(
    const float* __restrict__ ybar, const float* __restrict__ hw, const float* __restrict__ hb,
    float* __restrict__ out)
{
  __shared__ float ys[D_];
  int b = blockIdx.x >> 2;
  int c = (blockIdx.x & 3)*256 + threadIdx.x;
  for (int i = threadIdx.x; i < D_; i += 256) ys[i] = ybar[b*D_+i];
  __syncthreads();
  if (c < NCLS_) {
    float acc = hb[c];
    const float* wr = hw + (size_t)c*D_;
    for (int dd = 0; dd < D_; dd += 4) {
      float4 a4 = *reinterpret_cast<const float4*>(&ys[dd]);
      float4 b4 = *reinterpret_cast<const float4*>(&wr[dd]);
      acc += a4.x*b4.x + a4.y*b4.y + a4.z*b4.z + a4.w*b4.w;
    }
    out[(size_t)b*NCLS_ + c] = acc;
  }
}

extern "C" void kernel_launch(void* const* d_in, const int* in_sizes, int n_in,
                              void* d_out, int out_size, void* d_ws, size_t ws_size,
                              hipStream_t stream)
{
  const float* x          = (const float*)d_in[0];
  const float* patch_w    = (const float*)d_in[1];
  const float* patch_b    = (const float*)d_in[2];
  const float* pe_ln_w    = (const float*)d_in[3];
  const float* pe_ln_b    = (const float*)d_in[4];
  const float* ln_w       = (const float*)d_in[5];
  const float* ln_b       = (const float*)d_in[6];
  const float* in_proj_w  = (const float*)d_in[7];
  const float* conv_w     = (const float*)d_in[8];
  const float* conv_b     = (const float*)d_in[9];
  const float* x_proj_w   = (const float*)d_in[10];
  const float* dt_w       = (const float*)d_in[11];
  const float* dt_b       = (const float*)d_in[12];
  const float* A_log      = (const float*)d_in[13];
  const float* Dp         = (const float*)d_in[14];
  const float* out_proj_w = (const float*)d_in[15];
  const float* out_norm_w = (const float*)d_in[16];
  const float* out_norm_b = (const float*)d_in[17];
  const float* head_ln_w  = (const float*)d_in[18];
  const float* head_ln_b  = (const float*)d_in[19];
  const float* head_w     = (const float*)d_in[20];
  const float* head_b     = (const float*)d_in[21];
  float* out = (float*)d_out;

  float* ws = (float*)d_ws;
  float*    residual = ws;                          // 1,204,224 f32
  float*    xz       = residual + 1204224;          // 4,816,896 f32
  float*    u        = xz + 4816896;                // 2,408,448 f32
  float*    xdbl     = u + 2408448;                 //   275,968 f32
  ushort_t* u_bf     = (ushort_t*)(xdbl + 275968);  // 2,408,448 ush
  ushort_t* yg_bf    = u_bf + 2408448;              // 2,408,448 ush
  ushort_t* xln_bf   = yg_bf + 2408448;             // 1,204,224 ush
  ushort_t* wbf      = xln_bf + 1204224;
  ushort_t* pw_bf    = wbf;                         //   147,456 ush
  ushort_t* inw_bf   = wbf + 147456;                // 4,718,592 ush
  ushort_t* outw_bf  = inw_bf + 4718592;            // 2,359,296 ush
  ushort_t* xw_bf    = outw_bf + 2359296;           //   786,432 ush
  // patch-phase aliases inside xz (xz not yet written):
  ushort_t* Xp       = (ushort_t*)xz;               // 1,204,224 ush
  float*    C_patch  = xz + 602112;                 //   301,056 f32
  // tail aliases inside u (dead after last scan):
  float*    ynorm    = u;                           //   301,056 f32
  float*    ybar     = u + 301056;                  //     1,536 f32

  // weight conversions
  k_cvt3<<<(1806336+255)/256, 256, 0, stream>>>(patch_w, in_proj_w, out_proj_w, wbf);
  k_cvt_xw<<<(32*64*384+255)/256, 256, 0, stream>>>(x_proj_w, xw_bf);

  // patch embed: im2col -> mfma gemm -> double LN + scatter
  k_im2col<<<(ROWS_PER_DIR*768+255)/256, 256, 0, stream>>>(x, Xp);
  k_gemm2<768><<<dim3(ROWS_PER_DIR/32, 3), 64, 0, stream>>>(
      Xp, pw_bf, C_patch, D_, D_, 0, ROWS_PER_DIR);
  k_peln<<<ROWS_PER_DIR, 64, 0, stream>>>(C_patch, patch_b, pe_ln_w, pe_ln_b,
                                          ln_w, ln_b, residual, xln_bf);

  for (int layer = 0; layer < DEPTH_; ++layer) {
    k_gemm2<192><<<dim3(M_TOTAL/32, 12), 64, 0, stream>>>(
        xln_bf, inw_bf + (size_t)layer*768*D_, xz, 768, 768, DEPTH_*768*D_, ROWS_PER_DIR);
    k_conv<<<(M_TOTAL*96+255)/256, 256, 0, stream>>>(xz, conv_w, conv_b, u, u_bf, layer);
    k_gemm2<384><<<dim3(M_TOTAL/32, 1), 64, 0, stream>>>(
        u_bf, xw_bf + (size_t)layer*64*384, xdbl, 44, 44, DEPTH_*64*384, ROWS_PER_DIR);
    k_scan<<<4*B_*24, 256, 0, stream>>>(u, xdbl, xz, A_log, Dp, dt_w, dt_b, yg_bf, layer);
    if (layer < DEPTH_-1)
      k_outln<0><<<M_TOTAL/32, 384, 0, stream>>>(
          yg_bf, outw_bf, residual, ln_w, ln_b, xln_bf, layer);
    else
      k_outln<1><<<M_TOTAL/32, 384, 0, stream>>>(
          yg_bf, outw_bf, residual, ln_w, ln_b, xln_bf, layer);
  }

  k_combine<<<B_*L_, 64, 0, stream>>>(residual, out_norm_w, out_norm_b,
                                      head_ln_w, head_ln_b, ynorm);
  k_mean<<<B_, 192, 0, stream>>>(ynorm, ybar);
  k_head<<<B_*4, 256, 0, stream>>>(ybar, head_w, head_b, out);
}

// Round 10
// 669.149 us; speedup vs baseline: 1.0768x; 1.0086x over previous
//
#include <hip/hip_runtime.h>

#define B_ 8
#define IMGSZ 224
#define PATCH 16
#define D_ 192
#define DEPTH_ 8
#define H_ 14
#define W_ 14
#define L_ 196
#define DIN 384
#define DSTATE 16
#define DCONV 4
#define DTR 12
#define NCLS_ 1000
#define EPS_ 1e-5f
#define ROWS_PER_DIR (B_*L_)      /* 1568 */
#define M_TOTAL (4*ROWS_PER_DIR)  /* 6272 */

typedef unsigned short ushort_t;
typedef unsigned int uint_t;
typedef __attribute__((ext_vector_type(8)))  short bf16x8;
typedef __attribute__((ext_vector_type(16))) float f32x16;

__device__ __forceinline__ ushort_t f2bf(float f) {
  uint_t u = __builtin_bit_cast(uint_t, f);
  u += 0x7fffu + ((u >> 16) & 1u);          // RNE
  return (ushort_t)(u >> 16);
}

// ---- merged init: weight cvt (3 arrays) | x_proj_w pad-cvt | im2col ------
// block ranges: [0,7056) cvt3 | [7056,10128) cvt_xw | [10128,14832) im2col
__global__ __launch_bounds__(256) void k_init(
    const float* __restrict__ pw, const float* __restrict__ inw,
    const float* __restrict__ outw, ushort_t* __restrict__ wbf,
    const float* __restrict__ xwsrc, ushort_t* __restrict__ xwdst,
    const float* __restrict__ x, ushort_t* __restrict__ Xp)
{
  int bid = blockIdx.x;
  int tid = threadIdx.x;
  if (bid < 7056) {
    int i = bid*256 + tid;                      // float4 index
    if (i >= 1806336) return;
    const float* src;
    int off;
    if (i < 36864)        { src = pw;  off = i; }
    else if (i < 1216512) { src = inw; off = i - 36864; }
    else                  { src = outw; off = i - 1216512; }
    float4 v = reinterpret_cast<const float4*>(src)[off];
    ushort4 o;
    o.x = f2bf(v.x); o.y = f2bf(v.y); o.z = f2bf(v.z); o.w = f2bf(v.w);
    reinterpret_cast<ushort4*>(wbf)[i] = o;
  } else if (bid < 10128) {
    int idx = (bid - 7056)*256 + tid;
    if (idx >= 32*64*384) return;
    int g = idx / (64*384);
    int r = (idx / 384) % 64;
    int k = idx % 384;
    float v = (r < 44) ? xwsrc[((size_t)g*44 + r)*384 + k] : 0.f;
    xwdst[idx] = f2bf(v);
  } else {
    int idx = (bid - 10128)*256 + tid;
    if (idx >= ROWS_PER_DIR*768) return;
    int row = idx / 768, k = idx - row*768;
    int b = row / L_, l = row - b*L_;
    int hh = l / W_, ww = l - hh*W_;
    int c = k >> 8, rem = k & 255, pi = rem >> 4, pj = rem & 15;
    float v = x[(((size_t)b*3 + c)*IMGSZ + hh*PATCH + pi)*IMGSZ + ww*PATCH + pj];
    Xp[idx] = f2bf(v);
  }
}

// ------- MFMA bf16 GEMM, 32 rows x 64 cols per wave: C = X W^T (f32) ------
template<int KT>
__global__ __launch_bounds__(64) void k_gemm2(
    const ushort_t* __restrict__ X, const ushort_t* __restrict__ W,
    float* __restrict__ C, int N, int nb, int wstride, int rows_per_dir)
{
  int row0 = blockIdx.x*32, col0 = blockIdx.y*64;
  int dir = row0 / rows_per_dir;
  const ushort_t* Wp = W + (size_t)dir*wstride;
  int l = threadIdx.x;
  int r31 = l & 31, khalf = (l >> 5)*8;
  const ushort_t* aptr  = X  + (size_t)(row0 + r31)*KT + khalf;
  const ushort_t* b0ptr = Wp + (size_t)(col0 + r31)*KT + khalf;
  const ushort_t* b1ptr = b0ptr + (size_t)32*KT;
  f32x16 acc00 = {}, acc01 = {}, acc10 = {}, acc11 = {};
  #pragma unroll
  for (int k = 0; k < KT; k += 32) {
    bf16x8 a0 = *reinterpret_cast<const bf16x8*>(aptr + k);
    bf16x8 a1 = *reinterpret_cast<const bf16x8*>(aptr + k + 16);
    bf16x8 b00 = *reinterpret_cast<const bf16x8*>(b0ptr + k);
    bf16x8 b01 = *reinterpret_cast<const bf16x8*>(b0ptr + k + 16);
    bf16x8 b10 = *reinterpret_cast<const bf16x8*>(b1ptr + k);
    bf16x8 b11 = *reinterpret_cast<const bf16x8*>(b1ptr + k + 16);
    acc00 = __builtin_amdgcn_mfma_f32_32x32x16_bf16(a0, b00, acc00, 0, 0, 0);
    acc01 = __builtin_amdgcn_mfma_f32_32x32x16_bf16(a1, b01, acc01, 0, 0, 0);
    acc10 = __builtin_amdgcn_mfma_f32_32x32x16_bf16(a0, b10, acc10, 0, 0, 0);
    acc11 = __builtin_amdgcn_mfma_f32_32x32x16_bf16(a1, b11, acc11, 0, 0, 0);
  }
  int c0 = col0 + r31, c1 = col0 + 32 + r31;
  #pragma unroll
  for (int r = 0; r < 16; ++r) {
    int row = (r & 3) + 8*(r >> 2) + 4*(l >> 5);
    float* crow = C + (size_t)(row0 + row)*N;
    if (c0 < nb) crow[c0] = acc00[r] + acc01[r];
    if (c1 < nb) crow[c1] = acc10[r] + acc11[r];
  }
}

// ------- patch LN + layer-0 LN + scatter residual/xln to 4 directions -----
__global__ __launch_bounds__(64) void k_peln(
    const float* __restrict__ Cp, const float* __restrict__ pb,
    const float* __restrict__ plw, const float* __restrict__ plb,
    const float* __restrict__ lnw, const float* __restrict__ lnb,
    float* __restrict__ residual, ushort_t* __restrict__ xln)
{
  int blk = blockIdx.x;            // b*L + l
  int b = blk / L_, l = blk - b*L_;
  int hh = l / W_, ww = l - hh*W_;
  int lane = threadIdx.x;
  float v[3]; float s = 0.f;
  #pragma unroll
  for (int i = 0; i < 3; ++i) {
    int d = lane + i*64;
    float t = Cp[(size_t)blk*D_ + d] + pb[d];
    v[i] = t; s += t;
  }
  #pragma unroll
  for (int off = 32; off; off >>= 1) s += __shfl_xor(s, off);
  float m = s*(1.f/D_); float q = 0.f;
  #pragma unroll
  for (int i = 0; i < 3; ++i) { float dd = v[i]-m; q += dd*dd; }
  #pragma unroll
  for (int off = 32; off; off >>= 1) q += __shfl_xor(q, off);
  float inv = rsqrtf(q*(1.f/D_)+EPS_);
  float nv[3]; s = 0.f;
  #pragma unroll
  for (int i = 0; i < 3; ++i) {
    int d = lane + i*64;
    nv[i] = (v[i]-m)*inv*plw[d] + plb[d];
    s += nv[i];
  }
  #pragma unroll
  for (int off = 32; off; off >>= 1) s += __shfl_xor(s, off);
  float m2 = s*(1.f/D_); q = 0.f;
  #pragma unroll
  for (int i = 0; i < 3; ++i) { float dd = nv[i]-m2; q += dd*dd; }
  #pragma unroll
  for (int off = 32; off; off >>= 1) q += __shfl_xor(q, off);
  float inv2 = rsqrtf(q*(1.f/D_)+EPS_);
  int l1 = ww*W_ + hh;
  size_t rr[4];
  rr[0] = ((size_t)(0*B_+b))*L_ + l;
  rr[1] = ((size_t)(1*B_+b))*L_ + l1;
  rr[2] = ((size_t)(2*B_+b))*L_ + (L_-1-l);
  rr[3] = ((size_t)(3*B_+b))*L_ + (L_-1-l1);
  #pragma unroll
  for (int i = 0; i < 3; ++i) {
    int d = lane + i*64;
    float nrm = (nv[i]-m2)*inv2;
    #pragma unroll
    for (int k = 0; k < 4; ++k) {
      residual[rr[k]*D_+d] = nv[i];
      xln[rr[k]*D_+d] = f2bf(nrm*lnw[(size_t)(k*DEPTH_)*D_+d] + lnb[(size_t)(k*DEPTH_)*D_+d]);
    }
  }
}

// ---------------- causal depthwise conv (k=4) + bias + SiLU, float4 -------
// writes f32 u (for scan) and bf16 u (for x_proj MFMA GEMM)
__global__ __launch_bounds__(256) void k_conv(
    const float* __restrict__ xz, const float* __restrict__ cw, const float* __restrict__ cb,
    float* __restrict__ u, ushort_t* __restrict__ ub, int layer)
{
  int idx = blockIdx.x*256 + threadIdx.x;
  if (idx >= M_TOTAL*96) return;
  int row = idx / 96, d4 = (idx - row*96)*4;
  int kdir = row / ROWS_PER_DIR;
  int l = row % L_;
  size_t pbase = (size_t)(kdir*DEPTH_+layer)*DIN + d4;
  const float* cwp = cw + pbase*DCONV;
  float wv[16];
  #pragma unroll
  for (int i = 0; i < 4; ++i)
    ((float4*)wv)[i] = ((const float4*)cwp)[i];
  float4 bias = *reinterpret_cast<const float4*>(&cb[pbase]);
  float acc[4] = {bias.x, bias.y, bias.z, bias.w};
  #pragma unroll
  for (int t = 0; t < DCONV; ++t) {
    int ll = l - 3 + t;
    if (ll >= 0) {
      float4 xv = *reinterpret_cast<const float4*>(&xz[((size_t)row + (ll - l))*768 + d4]);
      acc[0] += xv.x * wv[0*4 + t];
      acc[1] += xv.y * wv[1*4 + t];
      acc[2] += xv.z * wv[2*4 + t];
      acc[3] += xv.w * wv[3*4 + t];
    }
  }
  float4 o; ushort4 ob;
  o.x = acc[0] / (1.f + __expf(-acc[0]));
  o.y = acc[1] / (1.f + __expf(-acc[1]));
  o.z = acc[2] / (1.f + __expf(-acc[2]));
  o.w = acc[3] / (1.f + __expf(-acc[3]));
  ob.x = f2bf(o.x); ob.y = f2bf(o.y); ob.z = f2bf(o.z); ob.w = f2bf(o.w);
  *reinterpret_cast<float4*>(&u[(size_t)row*DIN + d4]) = o;
  *reinterpret_cast<ushort4*>(&ub[(size_t)row*DIN + d4]) = ob;
}

// ------- selective scan with inline delta-proj + skip(D) + SiLU(z) gate ---
// block: 16 channels x 16 states; grid: 4*8*24; chunked, shuffle-free.
#define SCHUNK 14
#define NCHUNK 14
__global__ __launch_bounds__(256, 3) void k_scan(
    const float* __restrict__ u, const float* __restrict__ xdbl,
    const float* __restrict__ xz,
    const float* __restrict__ Alog, const float* __restrict__ Dp,
    const float* __restrict__ dtw, const float* __restrict__ dtb,
    ushort_t* __restrict__ yg, int layer)
{
  int blk = blockIdx.x;
  int kdir = blk / (B_*24);
  int rem = blk % (B_*24);
  int b = rem / 24, dc = rem % 24;
  int tid = threadIdx.x;
  int st = tid & 15, ch = tid >> 4;           // compute mapping
  size_t pl = (size_t)(kdir*DEPTH_+layer)*DIN + dc*16 + ch;
  float a = -expf(Alog[pl*DSTATE + st]);
  size_t rowbase = ((size_t)kdir*B_ + b)*L_;

  int ll = tid >> 4, cc = tid & 15;           // loader/phase3 mapping
  bool ldr = tid < 224;
  size_t plc = (size_t)(kdir*DEPTH_+layer)*DIN + dc*16 + cc;
  float Dv3 = Dp[plc];
  // per-thread dt weights (channel cc) for inline delta
  float dwt[12]; float dbias = dtb[plc];
  #pragma unroll
  for (int i = 0; i < 3; ++i)
    ((float4*)dwt)[i] = ((const float4*)(dtw + plc*DTR))[i];

  __shared__ __align__(16) float sd[16][20], su[16][20], sB[16][20],
                                 sC[16][20], sz[16][20];
  __shared__ __align__(16) float sp[SCHUNK][16][20];

  float rd=0.f, ru=0.f, rB=0.f, rC=0.f, rz=0.f;
  if (ldr) {
    size_t r = rowbase + ll;
    float xv[12];
    #pragma unroll
    for (int i = 0; i < 3; ++i) ((float4*)xv)[i] = ((const float4*)(xdbl + r*44))[i];
    float acc = dbias;
    #pragma unroll
    for (int t = 0; t < DTR; ++t) acc += xv[t]*dwt[t];
    rd = (acc > 20.f) ? acc : log1pf(__expf(acc));
    ru = u[r*DIN + dc*16 + cc];
    rB = xdbl[r*44 + DTR + cc];
    rC = xdbl[r*44 + DTR + DSTATE + cc];
    rz = xz[r*768 + DIN + dc*16 + cc];
  }

  float h = 0.f;
  for (int chk = 0; chk < NCHUNK; ++chk) {
    if (ldr) { sd[cc][ll]=rd; su[cc][ll]=ru; sB[cc][ll]=rB; sC[cc][ll]=rC; sz[cc][ll]=rz; }
    __syncthreads();
    if (chk+1 < NCHUNK && ldr) {
      size_t r = rowbase + (chk+1)*SCHUNK + ll;
      float xv[12];
      #pragma unroll
      for (int i = 0; i < 3; ++i) ((float4*)xv)[i] = ((const float4*)(xdbl + r*44))[i];
      float acc = dbias;
      #pragma unroll
      for (int t = 0; t < DTR; ++t) acc += xv[t]*dwt[t];
      rd = (acc > 20.f) ? acc : log1pf(__expf(acc));
      ru = u[r*DIN + dc*16 + cc];
      rB = xdbl[r*44 + DTR + cc];
      rC = xdbl[r*44 + DTR + DSTATE + cc];
      rz = xz[r*768 + DIN + dc*16 + cc];
    }
    // phase 1: bulk-load coefficient rows, compute all E (parallel exps)
    float dlv[16], ulv[16], Bvv[16], Cvv[16];
    #pragma unroll
    for (int i = 0; i < 4; ++i) {
      ((float4*)dlv)[i] = ((const float4*)&sd[ch][0])[i];
      ((float4*)ulv)[i] = ((const float4*)&su[ch][0])[i];
      ((float4*)Bvv)[i] = ((const float4*)&sB[st][0])[i];
      ((float4*)Cvv)[i] = ((const float4*)&sC[st][0])[i];
    }
    float E[SCHUNK];
    #pragma unroll
    for (int l = 0; l < SCHUNK; ++l) E[l] = __expf(dlv[l]*a);
    // phase 2: 14-FMA recurrence chain, store h*C
    #pragma unroll
    for (int l = 0; l < SCHUNK; ++l) {
      h = h*E[l] + dlv[l]*ulv[l]*Bvv[l];
      sp[l][ch][st] = h*Cvv[l];
    }
    __syncthreads();
    // phase 3: reduce 16 states per (l, ch), gate, coalesced store
    if (ldr) {
      float pv[16];
      #pragma unroll
      for (int i = 0; i < 4; ++i)
        ((float4*)pv)[i] = ((const float4*)&sp[ll][cc][0])[i];
      float s = 0.f;
      #pragma unroll
      for (int i = 0; i < 16; ++i) s += pv[i];
      float ul = su[cc][ll];
      float z  = sz[cc][ll];
      float yv = (s + ul*Dv3) * (z / (1.f + __expf(-z)));
      yg[(rowbase + chk*SCHUNK + ll)*DIN + dc*16 + cc] = f2bf(yv);
    }
    __syncthreads();
  }
}

// ------ fused out_proj GEMM + residual add + LN(layer+1) -> xln_bf --------
// grid 196 blocks x 384 threads (6 waves, one 32x32 col tile each)
template<int LAST>
__global__ __launch_bounds__(384) void k_outln(
    const ushort_t* __restrict__ X, const ushort_t* __restrict__ W,
    float* __restrict__ residual,
    const float* __restrict__ lnw, const float* __restrict__ lnb,
    ushort_t* __restrict__ xln, int layer)
{
  int row0 = blockIdx.x*32;
  int dir = row0 / ROWS_PER_DIR;
  const ushort_t* Wp = W + (size_t)dir*(DEPTH_*D_*DIN);
  int tid = threadIdx.x;
  int wv = tid >> 6;           // 0..5 -> col tile
  int l  = tid & 63;
  int col0 = wv*32;
  int r31 = l & 31, khalf = (l >> 5)*8;
  const ushort_t* aptr = X  + (size_t)(row0 + r31)*DIN + khalf;
  const ushort_t* bptr = Wp + (size_t)(col0 + r31)*DIN + khalf;
  f32x16 acc0 = {}, acc1 = {};
  #pragma unroll
  for (int k = 0; k < DIN; k += 32) {
    bf16x8 a0 = *reinterpret_cast<const bf16x8*>(aptr + k);
    bf16x8 b0 = *reinterpret_cast<const bf16x8*>(bptr + k);
    bf16x8 a1 = *reinterpret_cast<const bf16x8*>(aptr + k + 16);
    bf16x8 b1 = *reinterpret_cast<const bf16x8*>(bptr + k + 16);
    acc0 = __builtin_amdgcn_mfma_f32_32x32x16_bf16(a0, b0, acc0, 0, 0, 0);
    acc1 = __builtin_amdgcn_mfma_f32_32x32x16_bf16(a1, b1, acc1, 0, 0, 0);
  }
  __shared__ __align__(16) float Cs[32][196];
  __shared__ float sred[32][12], qred[32][12], sm[32], si[32];
  #pragma unroll
  for (int r = 0; r < 16; ++r) {
    int row = (r & 3) + 8*(r >> 2) + 4*(l >> 5);
    Cs[row][col0 + r31] = acc0[r] + acc1[r];
  }
  __syncthreads();
  // epilogue: 32 rows x 12 threads x 16 cols
  int rr = tid / 12, jj = tid - rr*12;
  int c0 = jj*16;
  float* resrow = residual + (size_t)(row0+rr)*D_ + c0;
  float v[16];
  float s = 0.f, q = 0.f;
  #pragma unroll
  for (int i = 0; i < 16; i += 4) {
    float4 rv = *reinterpret_cast<const float4*>(resrow + i);
    float4 cv = *reinterpret_cast<const float4*>(&Cs[rr][c0 + i]);
    v[i+0] = rv.x + cv.x; v[i+1] = rv.y + cv.y;
    v[i+2] = rv.z + cv.z; v[i+3] = rv.w + cv.w;
  }
  #pragma unroll
  for (int i = 0; i < 16; ++i) { s += v[i]; q += v[i]*v[i]; }
  // store residual_new
  #pragma unroll
  for (int i = 0; i < 16; i += 4) {
    float4 o = make_float4(v[i], v[i+1], v[i+2], v[i+3]);
    *reinterpret_cast<float4*>(resrow + i) = o;
  }
  if (!LAST) {
    sred[rr][jj] = s; qred[rr][jj] = q;
    __syncthreads();
    if (tid < 32) {
      float S = 0.f, Q = 0.f;
      #pragma unroll
      for (int j = 0; j < 12; ++j) { S += sred[tid][j]; Q += qred[tid][j]; }
      float m = S*(1.f/D_);
      float var = Q*(1.f/D_) - m*m;
      sm[tid] = m; si[tid] = rsqrtf(var + EPS_);
    }
    __syncthreads();
    float m = sm[rr], inv = si[rr];
    const float* w = lnw + (size_t)(dir*DEPTH_ + layer + 1)*D_ + c0;
    const float* bb = lnb + (size_t)(dir*DEPTH_ + layer + 1)*D_ + c0;
    ushort_t* xrow = xln + (size_t)(row0+rr)*D_ + c0;
    #pragma unroll
    for (int i = 0; i < 16; ++i)
      xrow[i] = f2bf((v[i]-m)*inv*w[i] + bb[i]);
  }
}

// ---------------- merge 4 directions + out_norm LN + head LN --------------
__global__ __launch_bounds__(64) void k_combine(
    const float* __restrict__ res,
    const float* __restrict__ onw, const float* __restrict__ onb,
    const float* __restrict__ hlw, const float* __restrict__ hlb,
    float* __restrict__ ynorm)
{
  int blk = blockIdx.x;
  int b = blk / L_, l = blk % L_;
  int hh = l / W_, ww = l % W_;
  int l1 = ww*W_ + hh;
  size_t r0 = ((size_t)(0*B_+b))*L_ + l;
  size_t r1 = ((size_t)(1*B_+b))*L_ + l1;
  size_t r2 = ((size_t)(2*B_+b))*L_ + (L_-1-l);
  size_t r3 = ((size_t)(3*B_+b))*L_ + (L_-1-l1);
  int lane = threadIdx.x;
  float v[3]; float s = 0.f;
  #pragma unroll
  for (int i=0;i<3;i++){
    int d = lane + i*64;
    float t = res[r0*D_+d] + res[r1*D_+d] + res[r2*D_+d] + res[r3*D_+d];
    v[i]=t; s+=t;
  }
  #pragma unroll
  for (int off=32;off;off>>=1) s += __shfl_xor(s,off);
  float m = s*(1.f/D_); float q=0.f;
  #pragma unroll
  for (int i=0;i<3;i++){ float dd=v[i]-m; q+=dd*dd; }
  #pragma unroll
  for (int off=32;off;off>>=1) q += __shfl_xor(q,off);
  float inv = rsqrtf(q*(1.f/D_)+EPS_);
  float v2[3]; s = 0.f;
  #pragma unroll
  for (int i=0;i<3;i++){ int d=lane+i*64; float t=(v[i]-m)*inv*onw[d]+onb[d]; v2[i]=t; s+=t; }
  #pragma unroll
  for (int off=32;off;off>>=1) s += __shfl_xor(s,off);
  float m2 = s*(1.f/D_); q=0.f;
  #pragma unroll
  for (int i=0;i<3;i++){ float dd=v2[i]-m2; q+=dd*dd; }
  #pragma unroll
  for (int off=32;off;off>>=1) q += __shfl_xor(q,off);
  float inv2 = rsqrtf(q*(1.f/D_)+EPS_);
  #pragma unroll
  for (int i=0;i<3;i++){ int d=lane+i*64; ynorm[((size_t)b*L_+l)*D_+d] = (v2[i]-m2)*inv2*hlw[d]+hlb[d]; }
}

// ---------------- classifier head with inline mean over L -----------------
__global__ __launch_bounds__(256) void k_head(
    const float* __restrict__ ynorm, const float* __restrict__ hw,
    const float* __restrict__ hb, float* __restrict__ out)
{
  __shared__ float ys[D_];
  int b = blockIdx.x >> 2;
  int c = (blockIdx.x & 3)*256 + threadIdx.x;
  if (threadIdx.x < D_) {
    int d = threadIdx.x;
    float s = 0.f;
    for (int l = 0; l < L_; ++l) s += ynorm[((size_t)b*L_+l)*D_ + d];
    ys[d] = s * (1.f/L_);
  }
  __syncthreads();
  if (c < NCLS_) {
    float acc = hb[c];
    const float* wr = hw + (size_t)c*D_;
    for (int dd = 0; dd < D_; dd += 4) {
      float4 a4 = *reinterpret_cast<const float4*>(&ys[dd]);
      float4 b4 = *reinterpret_cast<const float4*>(&wr[dd]);
      acc += a4.x*b4.x + a4.y*b4.y + a4.z*b4.z + a4.w*b4.w;
    }
    out[(size_t)b*NCLS_ + c] = acc;
  }
}

extern "C" void kernel_launch(void* const* d_in, const int* in_sizes, int n_in,
                              void* d_out, int out_size, void* d_ws, size_t ws_size,
                              hipStream_t stream)
{
  const float* x          = (const float*)d_in[0];
  const float* patch_w    = (const float*)d_in[1];
  const float* patch_b    = (const float*)d_in[2];
  const float* pe_ln_w    = (const float*)d_in[3];
  const float* pe_ln_b    = (const float*)d_in[4];
  const float* ln_w       = (const float*)d_in[5];
  const float* ln_b       = (const float*)d_in[6];
  const float* in_proj_w  = (const float*)d_in[7];
  const float* conv_w     = (const float*)d_in[8];
  const float* conv_b     = (const float*)d_in[9];
  const float* x_proj_w   = (const float*)d_in[10];
  const float* dt_w       = (const float*)d_in[11];
  const float* dt_b       = (const float*)d_in[12];
  const float* A_log      = (const float*)d_in[13];
  const float* Dp         = (const float*)d_in[14];
  const float* out_proj_w = (const float*)d_in[15];
  const float* out_norm_w = (const float*)d_in[16];
  const float* out_norm_b = (const float*)d_in[17];
  const float* head_ln_w  = (const float*)d_in[18];
  const float* head_ln_b  = (const float*)d_in[19];
  const float* head_w     = (const float*)d_in[20];
  const float* head_b     = (const float*)d_in[21];
  float* out = (float*)d_out;

  float* ws = (float*)d_ws;
  float*    residual = ws;                          // 1,204,224 f32
  float*    xz       = residual + 1204224;          // 4,816,896 f32
  float*    u        = xz + 4816896;                // 2,408,448 f32
  float*    xdbl     = u + 2408448;                 //   275,968 f32
  ushort_t* u_bf     = (ushort_t*)(xdbl + 275968);  // 2,408,448 ush
  ushort_t* yg_bf    = u_bf + 2408448;              // 2,408,448 ush
  ushort_t* xln_bf   = yg_bf + 2408448;             // 1,204,224 ush
  ushort_t* wbf      = xln_bf + 1204224;
  ushort_t* pw_bf    = wbf;                         //   147,456 ush
  ushort_t* inw_bf   = wbf + 147456;                // 4,718,592 ush
  ushort_t* outw_bf  = inw_bf + 4718592;            // 2,359,296 ush
  ushort_t* xw_bf    = outw_bf + 2359296;           //   786,432 ush
  // patch-phase aliases inside xz (xz not yet written):
  ushort_t* Xp       = (ushort_t*)xz;               // 1,204,224 ush
  float*    C_patch  = xz + 602112;                 //   301,056 f32
  // tail alias inside u (dead after last scan):
  float*    ynorm    = u;                           //   301,056 f32

  // merged init: weight cvts + im2col (independent regions, one launch)
  k_init<<<14832, 256, 0, stream>>>(patch_w, in_proj_w, out_proj_w, wbf,
                                    x_proj_w, xw_bf, x, Xp);

  // patch embed: mfma gemm -> double LN + scatter
  k_gemm2<768><<<dim3(ROWS_PER_DIR/32, 3), 64, 0, stream>>>(
      Xp, pw_bf, C_patch, D_, D_, 0, ROWS_PER_DIR);
  k_peln<<<ROWS_PER_DIR, 64, 0, stream>>>(C_patch, patch_b, pe_ln_w, pe_ln_b,
                                          ln_w, ln_b, residual, xln_bf);

  for (int layer = 0; layer < DEPTH_; ++layer) {
    k_gemm2<192><<<dim3(M_TOTAL/32, 12), 64, 0, stream>>>(
        xln_bf, inw_bf + (size_t)layer*768*D_, xz, 768, 768, DEPTH_*768*D_, ROWS_PER_DIR);
    k_conv<<<(M_TOTAL*96+255)/256, 256, 0, stream>>>(xz, conv_w, conv_b, u, u_bf, layer);
    k_gemm2<384><<<dim3(M_TOTAL/32, 1), 64, 0, stream>>>(
        u_bf, xw_bf + (size_t)layer*64*384, xdbl, 44, 44, DEPTH_*64*384, ROWS_PER_DIR);
    k_scan<<<4*B_*24, 256, 0, stream>>>(u, xdbl, xz, A_log, Dp, dt_w, dt_b, yg_bf, layer);
    if (layer < DEPTH_-1)
      k_outln<0><<<M_TOTAL/32, 384, 0, stream>>>(
          yg_bf, outw_bf, residual, ln_w, ln_b, xln_bf, layer);
    else
      k_outln<1><<<M_TOTAL/32, 384, 0, stream>>>(
          yg_bf, outw_bf, residual, ln_w, ln_b, xln_bf, layer);
  }

  k_combine<<<B_*L_, 64, 0, stream>>>(residual, out_norm_w, out_norm_b,
                                      head_ln_w, head_ln_b, ynorm);
  k_head<<<B_*4, 256, 0, stream>>>(ynorm, head_w, head_b, out);
}